// Round 1
// baseline (1559.507 us; speedup 1.0000x reference)
//
#include <hip/hip_runtime.h>
#include <math.h>

#define EMBED 1024
#define HEADS 16
#define DH    64
#define BATCH 2
#define SEQ   2048
#define TQ    32   // Q rows per attention block

// ---------------------------------------------------------------------------
// Kernel 1: per-head QKV projection.
// grid = (BATCH*SEQ, 3), block = 256. blockIdx.y selects q/k/v.
// out layout: [B, H, S, DH]  (head-major so attention tiles are contiguous)
// ---------------------------------------------------------------------------
__global__ __launch_bounds__(256) void proj_kernel(
    const float* __restrict__ q, const float* __restrict__ k, const float* __restrict__ v,
    const float* __restrict__ Wq, const float* __restrict__ bq,
    const float* __restrict__ Wk, const float* __restrict__ bk,
    const float* __restrict__ Wv, const float* __restrict__ bv,
    float* __restrict__ qh, float* __restrict__ kh, float* __restrict__ vh)
{
    const int bs = blockIdx.x;            // b*SEQ + s
    const int which = blockIdx.y;
    const float* x; const float* W; const float* bias; float* out;
    if (which == 0)      { x = q; W = Wq; bias = bq; out = qh; }
    else if (which == 1) { x = k; W = Wk; bias = bk; out = kh; }
    else                 { x = v; W = Wv; bias = bv; out = vh; }

    __shared__ float xs[EMBED];
    __shared__ float Wt[DH][DH + 4];      // Wt[j][d] = W[d*DH + j]; +4 pad -> 2-way (free)

    const int t = threadIdx.x;

    // stage x row (1024 floats) and W (transposed) into LDS
    ((float4*)xs)[t] = ((const float4*)(x + (size_t)bs * EMBED))[t];
#pragma unroll
    for (int u = 0; u < 16; ++u) {
        int idx = t * 16 + u;             // 0..4095
        Wt[idx & 63][idx >> 6] = W[idx];
    }
    __syncthreads();

    const int lane = t & 63;              // = output dim d
    const int wave = t >> 6;              // h = wave + 4*kk

    float acc0 = 0.f, acc1 = 0.f, acc2 = 0.f, acc3 = 0.f;
#pragma unroll
    for (int j = 0; j < DH; ++j) {
        float w = Wt[j][lane];
        acc0 += xs[(wave +  0) * DH + j] * w;
        acc1 += xs[(wave +  4) * DH + j] * w;
        acc2 += xs[(wave +  8) * DH + j] * w;
        acc3 += xs[(wave + 12) * DH + j] * w;
    }
    const int b = bs / SEQ, s = bs % SEQ;
    const float bb = bias[lane];
    out[(((size_t)b * HEADS + (wave +  0)) * SEQ + s) * DH + lane] = acc0 + bb;
    out[(((size_t)b * HEADS + (wave +  4)) * SEQ + s) * DH + lane] = acc1 + bb;
    out[(((size_t)b * HEADS + (wave +  8)) * SEQ + s) * DH + lane] = acc2 + bb;
    out[(((size_t)b * HEADS + (wave + 12)) * SEQ + s) * DH + lane] = acc3 + bb;
}

// ---------------------------------------------------------------------------
// Kernel 2: flash-style masked attention, fp32.
// grid = (SEQ/TQ, BATCH*HEADS), block = 256.
// Each thread owns (row i = t/8, col-group cg = t%8 -> 8 output dims).
// K stored transposed in LDS (avoids read conflicts in the QK inner loop).
// ---------------------------------------------------------------------------
__global__ __launch_bounds__(256) void attn_kernel(
    const float* __restrict__ qh, const float* __restrict__ kh, const float* __restrict__ vh,
    const int* __restrict__ mask, float* __restrict__ ctx)
{
    const int qt = blockIdx.x;
    const int bh = blockIdx.y;
    const int b = bh >> 4, h = bh & 15;
    const int q0 = qt * TQ;

    __shared__ float Qt[TQ][DH + 4];
    __shared__ float Ktt[DH][64 + 4];     // [d][j]
    __shared__ float Vt[64][DH + 4];
    __shared__ float St[TQ][64 + 4];

    const int t  = threadIdx.x;
    const int i  = t >> 3;                // 0..31 : Q row
    const int cg = t & 7;                 // 0..7  : 8-wide col group

    // ---- load Q tile (each thread: 8 contiguous floats of its own row) ----
    {
        const float* src = qh + (((size_t)b * HEADS + h) * SEQ + q0 + i) * DH + cg * 8;
        *((float4*)&Qt[i][cg * 8 + 0]) = ((const float4*)src)[0];
        *((float4*)&Qt[i][cg * 8 + 4]) = ((const float4*)src)[1];
    }

    float O[8];
#pragma unroll
    for (int u = 0; u < 8; ++u) O[u] = 0.f;
    float m_run = -3.0e38f, l_run = 0.f;

    const float* kbase = kh + (((size_t)b * HEADS + h) * SEQ) * DH;
    const float* vbase = vh + (((size_t)b * HEADS + h) * SEQ) * DH;
    const int*   mrow  = mask + ((size_t)b * SEQ + q0) * SEQ;   // mask[b][0][q0+i][*]

    for (int kt = 0; kt < SEQ / 64; ++kt) {
        const int k0 = kt * 64;
        __syncthreads();                  // protect Ktt/Vt/St from prior readers

        // ---- stage K (transposed) and V: thread covers 16 elems ----
        {
            const int srow = t >> 2;
            const int db   = (t & 3) * 16;
            const float* ksrc = kbase + (size_t)(k0 + srow) * DH + db;
            const float* vsrc = vbase + (size_t)(k0 + srow) * DH + db;
#pragma unroll
            for (int u4 = 0; u4 < 4; ++u4) {
                float4 kv = ((const float4*)ksrc)[u4];
                Ktt[db + u4 * 4 + 0][srow] = kv.x;
                Ktt[db + u4 * 4 + 1][srow] = kv.y;
                Ktt[db + u4 * 4 + 2][srow] = kv.z;
                Ktt[db + u4 * 4 + 3][srow] = kv.w;
                ((float4*)&Vt[srow][db])[u4] = ((const float4*)vsrc)[u4];
            }
        }
        __syncthreads();

        // ---- scores: (i, j = cg*8 .. cg*8+7) ----
        float sc[8];
#pragma unroll
        for (int u = 0; u < 8; ++u) sc[u] = 0.f;
#pragma unroll 16
        for (int d = 0; d < DH; ++d) {
            float qv = Qt[i][d];
            float4 k0v = *((const float4*)&Ktt[d][cg * 8 + 0]);
            float4 k1v = *((const float4*)&Ktt[d][cg * 8 + 4]);
            sc[0] += qv * k0v.x; sc[1] += qv * k0v.y;
            sc[2] += qv * k0v.z; sc[3] += qv * k0v.w;
            sc[4] += qv * k1v.x; sc[5] += qv * k1v.y;
            sc[6] += qv * k1v.z; sc[7] += qv * k1v.w;
        }
        // mask BEFORE scale (matches reference), then * 1/sqrt(64)
        {
            const int* mp = mrow + (size_t)i * SEQ + k0 + cg * 8;
            int4 m0 = ((const int4*)mp)[0];
            int4 m1 = ((const int4*)mp)[1];
            sc[0] = (m0.x == 0) ? -1e20f : sc[0];
            sc[1] = (m0.y == 0) ? -1e20f : sc[1];
            sc[2] = (m0.z == 0) ? -1e20f : sc[2];
            sc[3] = (m0.w == 0) ? -1e20f : sc[3];
            sc[4] = (m1.x == 0) ? -1e20f : sc[4];
            sc[5] = (m1.y == 0) ? -1e20f : sc[5];
            sc[6] = (m1.z == 0) ? -1e20f : sc[6];
            sc[7] = (m1.w == 0) ? -1e20f : sc[7];
#pragma unroll
            for (int u = 0; u < 8; ++u) sc[u] *= 0.125f;
        }
        *((float4*)&St[i][cg * 8 + 0]) = make_float4(sc[0], sc[1], sc[2], sc[3]);
        *((float4*)&St[i][cg * 8 + 4]) = make_float4(sc[4], sc[5], sc[6], sc[7]);
        __syncthreads();

        // ---- online softmax + PV (8 threads per row do stats redundantly) ----
        float mt = -3.0e38f;
#pragma unroll 16
        for (int j = 0; j < 64; ++j) mt = fmaxf(mt, St[i][j]);
        float newm = fmaxf(m_run, mt);
        float corr = __expf(m_run - newm);
        l_run *= corr;
#pragma unroll
        for (int u = 0; u < 8; ++u) O[u] *= corr;
        float lsum = 0.f;
#pragma unroll 8
        for (int j = 0; j < 64; ++j) {
            float p = __expf(St[i][j] - newm);
            lsum += p;
            float4 v0 = *((const float4*)&Vt[j][cg * 8 + 0]);
            float4 v1 = *((const float4*)&Vt[j][cg * 8 + 4]);
            O[0] += p * v0.x; O[1] += p * v0.y;
            O[2] += p * v0.z; O[3] += p * v0.w;
            O[4] += p * v1.x; O[5] += p * v1.y;
            O[6] += p * v1.z; O[7] += p * v1.w;
        }
        l_run += lsum;
        m_run = newm;
    }

    const float inv = 1.0f / l_run;
    float* dst = ctx + (((size_t)b * HEADS + h) * SEQ + q0 + i) * DH + cg * 8;
    ((float4*)dst)[0] = make_float4(O[0] * inv, O[1] * inv, O[2] * inv, O[3] * inv);
    ((float4*)dst)[1] = make_float4(O[4] * inv, O[5] * inv, O[6] * inv, O[7] * inv);
}

// ---------------------------------------------------------------------------
// Kernel 3: output projection  out[m,n] = sum_k ctx[m,k]*Wo[n,k] + bo[n]
// ctx layout [B,H,S,DH]; k-tile kt == head index -> contiguous A tile.
// grid = (16, 64), block = 256; 64x64 C tile, 16 outputs/thread.
// ---------------------------------------------------------------------------
__global__ __launch_bounds__(256) void outproj_kernel(
    const float* __restrict__ ctx, const float* __restrict__ Wo,
    const float* __restrict__ bo, float* __restrict__ out)
{
    const int n0 = blockIdx.x * 64;
    const int m0 = blockIdx.y * 64;
    const int b  = m0 / SEQ;
    const int s0 = m0 % SEQ;

    __shared__ float At[64][DH + 4];
    __shared__ float Wt[64][64 + 4];      // Wt[kk][nn] (transposed)

    const int t  = threadIdx.x;
    const int r  = t >> 2;                // C row within tile
    const int cg = t & 3;                 // 16-wide col group

    float acc[16];
#pragma unroll
    for (int u = 0; u < 16; ++u) acc[u] = 0.f;

    for (int kt = 0; kt < HEADS; ++kt) {
        __syncthreads();
        // A tile: contiguous 4096-float block for head kt
        {
            const float* asrc = ctx + (((size_t)b * HEADS + kt) * SEQ + s0) * DH + t * 16;
            float4* dst = (float4*)&At[t >> 2][(t & 3) * 16];
#pragma unroll
            for (int u4 = 0; u4 < 4; ++u4) dst[u4] = ((const float4*)asrc)[u4];
        }
        // Wo tile, transposed into LDS
        {
            const int nn = t >> 2;
            const int kb = (t & 3) * 16;
            const float* wsrc = Wo + (size_t)(n0 + nn) * EMBED + kt * 64 + kb;
#pragma unroll
            for (int u4 = 0; u4 < 4; ++u4) {
                float4 w = ((const float4*)wsrc)[u4];
                Wt[kb + u4 * 4 + 0][nn] = w.x;
                Wt[kb + u4 * 4 + 1][nn] = w.y;
                Wt[kb + u4 * 4 + 2][nn] = w.z;
                Wt[kb + u4 * 4 + 3][nn] = w.w;
            }
        }
        __syncthreads();
#pragma unroll 16
        for (int kk = 0; kk < 64; ++kk) {
            float av = At[r][kk];
            float4 w0 = *((const float4*)&Wt[kk][cg * 16 +  0]);
            float4 w1 = *((const float4*)&Wt[kk][cg * 16 +  4]);
            float4 w2 = *((const float4*)&Wt[kk][cg * 16 +  8]);
            float4 w3 = *((const float4*)&Wt[kk][cg * 16 + 12]);
            acc[ 0] += av * w0.x; acc[ 1] += av * w0.y; acc[ 2] += av * w0.z; acc[ 3] += av * w0.w;
            acc[ 4] += av * w1.x; acc[ 5] += av * w1.y; acc[ 6] += av * w1.z; acc[ 7] += av * w1.w;
            acc[ 8] += av * w2.x; acc[ 9] += av * w2.y; acc[10] += av * w2.z; acc[11] += av * w2.w;
            acc[12] += av * w3.x; acc[13] += av * w3.y; acc[14] += av * w3.z; acc[15] += av * w3.w;
        }
    }

    const float* bop = bo + n0 + cg * 16;
    float* dst = out + (size_t)(m0 + r) * EMBED + n0 + cg * 16;
#pragma unroll
    for (int u4 = 0; u4 < 4; ++u4) {
        float4 bv = ((const float4*)bop)[u4];
        ((float4*)dst)[u4] = make_float4(acc[u4 * 4 + 0] + bv.x, acc[u4 * 4 + 1] + bv.y,
                                         acc[u4 * 4 + 2] + bv.z, acc[u4 * 4 + 3] + bv.w);
    }
}

// ---------------------------------------------------------------------------
extern "C" void kernel_launch(void* const* d_in, const int* in_sizes, int n_in,
                              void* d_out, int out_size, void* d_ws, size_t ws_size,
                              hipStream_t stream) {
    const float* k    = (const float*)d_in[0];
    const float* q    = (const float*)d_in[1];
    const float* v    = (const float*)d_in[2];
    const int*   mask = (const int*)  d_in[3];
    const float* Wk   = (const float*)d_in[4];
    const float* bk   = (const float*)d_in[5];
    const float* Wq   = (const float*)d_in[6];
    const float* bq   = (const float*)d_in[7];
    const float* Wv   = (const float*)d_in[8];
    const float* bv   = (const float*)d_in[9];
    const float* Wo   = (const float*)d_in[10];
    const float* bo   = (const float*)d_in[11];
    float* out = (float*)d_out;

    const size_t TENSOR = (size_t)BATCH * SEQ * EMBED;   // 4,194,304 floats
    float* qh  = (float*)d_ws;
    float* kh  = qh + TENSOR;
    float* vh  = kh + TENSOR;
    float* ctx = vh + TENSOR;                            // total 64 MiB

    proj_kernel<<<dim3(BATCH * SEQ, 3), 256, 0, stream>>>(
        q, k, v, Wq, bq, Wk, bk, Wv, bv, qh, kh, vh);
    attn_kernel<<<dim3(SEQ / TQ, BATCH * HEADS), 256, 0, stream>>>(
        qh, kh, vh, mask, ctx);
    outproj_kernel<<<dim3(EMBED / 64, BATCH * SEQ / 64), 256, 0, stream>>>(
        ctx, Wo, bo, out);
}

// Round 2
// 422.239 us; speedup vs baseline: 3.6934x; 3.6934x over previous
//
#include <hip/hip_runtime.h>
#include <math.h>

#define EMBED 1024
#define HEADS 16
#define DH    64
#define BATCH 2
#define SEQ   2048

typedef __attribute__((ext_vector_type(8))) short bf16x8;
typedef __attribute__((ext_vector_type(4))) float f32x4;
typedef unsigned short ushort_t;
typedef unsigned long long u64;

static __device__ __forceinline__ unsigned short f2bf(float x) {
    unsigned u = __builtin_bit_cast(unsigned, x);
    return (unsigned short)((u + 0x7fffu + ((u >> 16) & 1u)) >> 16);
}

// ---------------------------------------------------------------------------
// Kernel 1: per-head QKV projection -> bf16 outputs, layout [B,H,S,DH].
// grid = (BATCH*SEQ, 3), block = 256.
// ---------------------------------------------------------------------------
__global__ __launch_bounds__(256) void proj_kernel(
    const float* __restrict__ q, const float* __restrict__ k, const float* __restrict__ v,
    const float* __restrict__ Wq, const float* __restrict__ bq,
    const float* __restrict__ Wk, const float* __restrict__ bk,
    const float* __restrict__ Wv, const float* __restrict__ bv,
    unsigned short* __restrict__ qh, unsigned short* __restrict__ kh,
    unsigned short* __restrict__ vh)
{
    const int bs = blockIdx.x;            // b*SEQ + s
    const int which = blockIdx.y;
    const float* x; const float* W; const float* bias; unsigned short* out;
    if (which == 0)      { x = q; W = Wq; bias = bq; out = qh; }
    else if (which == 1) { x = k; W = Wk; bias = bk; out = kh; }
    else                 { x = v; W = Wv; bias = bv; out = vh; }

    __shared__ float xs[EMBED];
    __shared__ float Wt[DH][DH + 4];      // Wt[j][d] = W[d*DH + j]

    const int t = threadIdx.x;

    ((float4*)xs)[t] = ((const float4*)(x + (size_t)bs * EMBED))[t];
#pragma unroll
    for (int u = 0; u < 16; ++u) {
        int idx = t * 16 + u;
        Wt[idx & 63][idx >> 6] = W[idx];
    }
    __syncthreads();

    const int lane = t & 63;              // output dim d
    const int wave = t >> 6;              // h = wave + 4*kk

    float acc0 = 0.f, acc1 = 0.f, acc2 = 0.f, acc3 = 0.f;
#pragma unroll
    for (int j = 0; j < DH; ++j) {
        float w = Wt[j][lane];
        acc0 += xs[(wave +  0) * DH + j] * w;
        acc1 += xs[(wave +  4) * DH + j] * w;
        acc2 += xs[(wave +  8) * DH + j] * w;
        acc3 += xs[(wave + 12) * DH + j] * w;
    }
    const int b = bs / SEQ, s = bs % SEQ;
    const float bb = bias[lane];
    out[(((size_t)b * HEADS + (wave +  0)) * SEQ + s) * DH + lane] = f2bf(acc0 + bb);
    out[(((size_t)b * HEADS + (wave +  4)) * SEQ + s) * DH + lane] = f2bf(acc1 + bb);
    out[(((size_t)b * HEADS + (wave +  8)) * SEQ + s) * DH + lane] = f2bf(acc2 + bb);
    out[(((size_t)b * HEADS + (wave + 12)) * SEQ + s) * DH + lane] = f2bf(acc3 + bb);
}

// ---------------------------------------------------------------------------
// Kernel 2: transpose V per head: vh [BH][S][64] -> vt [BH][64][S]  (bf16)
// grid = (SEQ/64, BATCH*HEADS), block = 256.
// ---------------------------------------------------------------------------
__global__ __launch_bounds__(256) void vtrans_kernel(
    const unsigned short* __restrict__ vh, unsigned short* __restrict__ vt)
{
    const int st = blockIdx.x;
    const int bh = blockIdx.y;
    __shared__ unsigned short Tt[64 * 72];

    const int t = threadIdx.x;
    const int r = t >> 2, p = t & 3;

    const unsigned short* src = vh + ((size_t)bh * SEQ + st * 64 + r) * DH + p * 16;
    *(uint4*)&Tt[r * 72 + p * 16]     = *(const uint4*)src;
    *(uint4*)&Tt[r * 72 + p * 16 + 8] = *(const uint4*)(src + 8);
    __syncthreads();

    union { unsigned short u[16]; uint4 v[2]; } o;
#pragma unroll
    for (int u = 0; u < 16; ++u) o.u[u] = Tt[(p * 16 + u) * 72 + r];
    unsigned short* dst = vt + ((size_t)bh * DH + r) * SEQ + st * 64 + p * 16;
    *(uint4*)dst       = o.v[0];
    *(uint4*)(dst + 8) = o.v[1];
}

// ---------------------------------------------------------------------------
// Kernel 3: pack int32 mask [B,1,S,S] into bitmask [B, S, S/64] (u64)
// ---------------------------------------------------------------------------
__global__ __launch_bounds__(256) void maskpack_kernel(
    const int* __restrict__ mask, u64* __restrict__ bits)
{
    const int idx = blockIdx.x * 256 + threadIdx.x;   // word index
    const int4* src = (const int4*)(mask + (size_t)idx * 64);
    u64 w = 0;
#pragma unroll
    for (int u = 0; u < 16; ++u) {
        int4 m = src[u];
        u64 nib = (m.x != 0 ? 1ull : 0) | (m.y != 0 ? 2ull : 0) |
                  (m.z != 0 ? 4ull : 0) | (m.w != 0 ? 8ull : 0);
        w |= nib << (u * 4);
    }
    bits[idx] = w;
}

// ---------------------------------------------------------------------------
// Kernel 4: MFMA flash attention (fixed-max softmax, bf16 in / fp32 accum).
// grid = (SEQ/64, BATCH*HEADS), block = 256 (4 waves; wave w owns 16 Q rows).
// qh/kh: bf16 [BH][S][64]; vt: bf16 [BH][64][S]; ctx: fp32 [BH][S][64].
// ---------------------------------------------------------------------------
__global__ __launch_bounds__(256) void attn_kernel(
    const unsigned short* __restrict__ qh, const unsigned short* __restrict__ kh,
    const unsigned short* __restrict__ vt, const u64* __restrict__ mbits,
    float* __restrict__ ctx)
{
    const int q0 = blockIdx.x * 64;
    const int bh = blockIdx.y;
    const int b  = bh >> 4;

    __shared__ unsigned short Kt[64 * 72];       // [j][d]
    __shared__ unsigned short Vt[64 * 72];       // [d][j]
    __shared__ unsigned short Pt[4 * 16 * 72];   // per-wave [i][j]

    const int t    = threadIdx.x;
    const int w    = t >> 6;
    const int lane = t & 63;
    const int l15  = lane & 15;
    const int quad = lane >> 4;

    // Q A-fragments (held in registers for the whole K loop)
    bf16x8 qf0, qf1;
    {
        const unsigned short* qb =
            qh + ((size_t)bh * SEQ + q0 + w * 16 + l15) * DH + quad * 8;
        qf0 = *(const bf16x8*)qb;
        qf1 = *(const bf16x8*)(qb + 32);
    }

    f32x4 O[4] = {f32x4{0,0,0,0}, f32x4{0,0,0,0}, f32x4{0,0,0,0}, f32x4{0,0,0,0}};
    float lsum[4] = {0.f, 0.f, 0.f, 0.f};

    const unsigned short* kbase = kh + (size_t)bh * SEQ * DH;
    const unsigned short* vbase = vt + (size_t)bh * DH * SEQ;
    const u64* mbase = mbits + ((size_t)b * SEQ + q0 + w * 16) * (SEQ / 64);

    const int sr = t >> 2, sp = t & 3;           // staging thread mapping

    for (int kt = 0; kt < SEQ / 64; ++kt) {
        __syncthreads();                         // all waves done with Kt/Vt
        {
            const unsigned short* ks = kbase + ((size_t)(kt * 64 + sr)) * DH + sp * 16;
            *(uint4*)&Kt[sr * 72 + sp * 16]     = *(const uint4*)ks;
            *(uint4*)&Kt[sr * 72 + sp * 16 + 8] = *(const uint4*)(ks + 8);
            const unsigned short* vs = vbase + (size_t)sr * SEQ + kt * 64 + sp * 16;
            *(uint4*)&Vt[sr * 72 + sp * 16]     = *(const uint4*)vs;
            *(uint4*)&Vt[sr * 72 + sp * 16 + 8] = *(const uint4*)(vs + 8);
        }
        __syncthreads();

        // ---- QK^T: 16x64 score stripe per wave ----
        f32x4 s[4];
#pragma unroll
        for (int st = 0; st < 4; ++st) {
            bf16x8 kf0 = *(const bf16x8*)&Kt[(st * 16 + l15) * 72 + quad * 8];
            bf16x8 kf1 = *(const bf16x8*)&Kt[(st * 16 + l15) * 72 + 32 + quad * 8];
            f32x4 acc = {0, 0, 0, 0};
            acc = __builtin_amdgcn_mfma_f32_16x16x32_bf16(qf0, kf0, acc, 0, 0, 0);
            acc = __builtin_amdgcn_mfma_f32_16x16x32_bf16(qf1, kf1, acc, 0, 0, 0);
            s[st] = acc;
        }

        // ---- mask + exp (fixed-max softmax) + pack P to LDS ----
        u64 rb0 = mbase[(quad * 4 + 0) * (SEQ / 64) + kt];
        u64 rb1 = mbase[(quad * 4 + 1) * (SEQ / 64) + kt];
        u64 rb2 = mbase[(quad * 4 + 2) * (SEQ / 64) + kt];
        u64 rb3 = mbase[(quad * 4 + 3) * (SEQ / 64) + kt];
#pragma unroll
        for (int st = 0; st < 4; ++st) {
            const int bitpos = st * 16 + l15;
            float p0 = ((rb0 >> bitpos) & 1ull) ? __expf(fminf(s[st][0] * 0.125f, 60.f)) : 0.f;
            float p1 = ((rb1 >> bitpos) & 1ull) ? __expf(fminf(s[st][1] * 0.125f, 60.f)) : 0.f;
            float p2 = ((rb2 >> bitpos) & 1ull) ? __expf(fminf(s[st][2] * 0.125f, 60.f)) : 0.f;
            float p3 = ((rb3 >> bitpos) & 1ull) ? __expf(fminf(s[st][3] * 0.125f, 60.f)) : 0.f;
            lsum[0] += p0; lsum[1] += p1; lsum[2] += p2; lsum[3] += p3;
            const int col = st * 16 + l15;
            Pt[(w * 16 + quad * 4 + 0) * 72 + col] = f2bf(p0);
            Pt[(w * 16 + quad * 4 + 1) * 72 + col] = f2bf(p1);
            Pt[(w * 16 + quad * 4 + 2) * 72 + col] = f2bf(p2);
            Pt[(w * 16 + quad * 4 + 3) * 72 + col] = f2bf(p3);
        }
        __threadfence_block();   // order Pt writes before wave-local reads

        // ---- PV: O += P * V ----
#pragma unroll
        for (int jc = 0; jc < 2; ++jc) {
            bf16x8 pf = *(const bf16x8*)&Pt[(w * 16 + l15) * 72 + jc * 32 + quad * 8];
#pragma unroll
            for (int st = 0; st < 4; ++st) {
                bf16x8 vf = *(const bf16x8*)&Vt[(st * 16 + l15) * 72 + jc * 32 + quad * 8];
                O[st] = __builtin_amdgcn_mfma_f32_16x16x32_bf16(pf, vf, O[st], 0, 0, 0);
            }
        }
    }

    // ---- final: reduce row sums across the 16 lanes of each quad-row ----
#pragma unroll
    for (int r = 0; r < 4; ++r) {
        float lr = lsum[r];
        lr += __shfl_xor(lr, 1);
        lr += __shfl_xor(lr, 2);
        lr += __shfl_xor(lr, 4);
        lr += __shfl_xor(lr, 8);
        const float inv = 1.0f / lr;
        float* dst = ctx + ((size_t)bh * SEQ + q0 + w * 16 + quad * 4 + r) * DH + l15;
        dst[0]  = O[0][r] * inv;
        dst[16] = O[1][r] * inv;
        dst[32] = O[2][r] * inv;
        dst[48] = O[3][r] * inv;
    }
}

// ---------------------------------------------------------------------------
// Kernel 5: output projection  out[m,n] = sum_k ctx[m,k]*Wo[n,k] + bo[n]
// ctx layout [B,H,S,DH] fp32; grid = (16, 64), block = 256.
// ---------------------------------------------------------------------------
__global__ __launch_bounds__(256) void outproj_kernel(
    const float* __restrict__ ctx, const float* __restrict__ Wo,
    const float* __restrict__ bo, float* __restrict__ out)
{
    const int n0 = blockIdx.x * 64;
    const int m0 = blockIdx.y * 64;
    const int b  = m0 / SEQ;
    const int s0 = m0 % SEQ;

    __shared__ float At[64][DH + 4];
    __shared__ float Wt[64][64 + 4];

    const int t  = threadIdx.x;
    const int r  = t >> 2;
    const int cg = t & 3;

    float acc[16];
#pragma unroll
    for (int u = 0; u < 16; ++u) acc[u] = 0.f;

    for (int kt = 0; kt < HEADS; ++kt) {
        __syncthreads();
        {
            const float* asrc = ctx + (((size_t)b * HEADS + kt) * SEQ + s0) * DH + t * 16;
            float4* dst = (float4*)&At[t >> 2][(t & 3) * 16];
#pragma unroll
            for (int u4 = 0; u4 < 4; ++u4) dst[u4] = ((const float4*)asrc)[u4];
        }
        {
            const int nn = t >> 2;
            const int kb = (t & 3) * 16;
            const float* wsrc = Wo + (size_t)(n0 + nn) * EMBED + kt * 64 + kb;
#pragma unroll
            for (int u4 = 0; u4 < 4; ++u4) {
                float4 wv = ((const float4*)wsrc)[u4];
                Wt[kb + u4 * 4 + 0][nn] = wv.x;
                Wt[kb + u4 * 4 + 1][nn] = wv.y;
                Wt[kb + u4 * 4 + 2][nn] = wv.z;
                Wt[kb + u4 * 4 + 3][nn] = wv.w;
            }
        }
        __syncthreads();
#pragma unroll 16
        for (int kk = 0; kk < 64; ++kk) {
            float av = At[r][kk];
            float4 w0 = *((const float4*)&Wt[kk][cg * 16 +  0]);
            float4 w1 = *((const float4*)&Wt[kk][cg * 16 +  4]);
            float4 w2 = *((const float4*)&Wt[kk][cg * 16 +  8]);
            float4 w3 = *((const float4*)&Wt[kk][cg * 16 + 12]);
            acc[ 0] += av * w0.x; acc[ 1] += av * w0.y; acc[ 2] += av * w0.z; acc[ 3] += av * w0.w;
            acc[ 4] += av * w1.x; acc[ 5] += av * w1.y; acc[ 6] += av * w1.z; acc[ 7] += av * w1.w;
            acc[ 8] += av * w2.x; acc[ 9] += av * w2.y; acc[10] += av * w2.z; acc[11] += av * w2.w;
            acc[12] += av * w3.x; acc[13] += av * w3.y; acc[14] += av * w3.z; acc[15] += av * w3.w;
        }
    }

    const float* bop = bo + n0 + cg * 16;
    float* dst = out + (size_t)(m0 + r) * EMBED + n0 + cg * 16;
#pragma unroll
    for (int u4 = 0; u4 < 4; ++u4) {
        float4 bv = ((const float4*)bop)[u4];
        ((float4*)dst)[u4] = make_float4(acc[u4 * 4 + 0] + bv.x, acc[u4 * 4 + 1] + bv.y,
                                         acc[u4 * 4 + 2] + bv.z, acc[u4 * 4 + 3] + bv.w);
    }
}

// ---------------------------------------------------------------------------
extern "C" void kernel_launch(void* const* d_in, const int* in_sizes, int n_in,
                              void* d_out, int out_size, void* d_ws, size_t ws_size,
                              hipStream_t stream) {
    const float* k    = (const float*)d_in[0];
    const float* q    = (const float*)d_in[1];
    const float* v    = (const float*)d_in[2];
    const int*   mask = (const int*)  d_in[3];
    const float* Wk   = (const float*)d_in[4];
    const float* bk   = (const float*)d_in[5];
    const float* Wq   = (const float*)d_in[6];
    const float* bq   = (const float*)d_in[7];
    const float* Wv   = (const float*)d_in[8];
    const float* bv   = (const float*)d_in[9];
    const float* Wo   = (const float*)d_in[10];
    const float* bo   = (const float*)d_in[11];
    float* out = (float*)d_out;

    const size_t TEN = (size_t)BATCH * HEADS * SEQ * DH;   // 4,194,304 elems
    unsigned short* qh_bf = (unsigned short*)d_ws;         // 8 MB
    unsigned short* kh_bf = qh_bf + TEN;                   // 8 MB
    unsigned short* vh_bf = kh_bf + TEN;                   // 8 MB
    unsigned short* vt_bf = vh_bf + TEN;                   // 8 MB
    float*          ctx   = (float*)(vt_bf + TEN);         // 16 MB
    u64*            mbits = (u64*)(ctx + TEN);             // 1 MB   (49 MB total)

    proj_kernel<<<dim3(BATCH * SEQ, 3), 256, 0, stream>>>(
        q, k, v, Wq, bq, Wk, bk, Wv, bv, qh_bf, kh_bf, vh_bf);
    vtrans_kernel<<<dim3(SEQ / 64, BATCH * HEADS), 256, 0, stream>>>(vh_bf, vt_bf);
    maskpack_kernel<<<dim3((BATCH * SEQ * (SEQ / 64)) / 256), 256, 0, stream>>>(mask, mbits);
    attn_kernel<<<dim3(SEQ / 64, BATCH * HEADS), 256, 0, stream>>>(
        qh_bf, kh_bf, vt_bf, mbits, ctx);
    outproj_kernel<<<dim3(EMBED / 64, BATCH * SEQ / 64), 256, 0, stream>>>(
        ctx, Wo, bo, out);
}

// Round 3
// 285.316 us; speedup vs baseline: 5.4659x; 1.4799x over previous
//
#include <hip/hip_runtime.h>
#include <math.h>

#define EMBED 1024
#define HEADS 16
#define DH    64
#define BATCH 2
#define SEQ   2048

typedef __attribute__((ext_vector_type(8))) short bf16x8;
typedef __attribute__((ext_vector_type(4))) float f32x4;
typedef unsigned long long u64;

static __device__ __forceinline__ unsigned short f2bf(float x) {
    unsigned u = __builtin_bit_cast(unsigned, x);
    return (unsigned short)((u + 0x7fffu + ((u >> 16) & 1u)) >> 16);
}

// ---------------------------------------------------------------------------
// Kernel 1: per-head QKV projection -> bf16 outputs, layout [B,H,S,DH].
// grid = (BATCH*SEQ, 3), block = 256.
// ---------------------------------------------------------------------------
__global__ __launch_bounds__(256) void proj_kernel(
    const float* __restrict__ q, const float* __restrict__ k, const float* __restrict__ v,
    const float* __restrict__ Wq, const float* __restrict__ bq,
    const float* __restrict__ Wk, const float* __restrict__ bk,
    const float* __restrict__ Wv, const float* __restrict__ bv,
    unsigned short* __restrict__ qh, unsigned short* __restrict__ kh,
    unsigned short* __restrict__ vh)
{
    const int bs = blockIdx.x;            // b*SEQ + s
    const int which = blockIdx.y;
    const float* x; const float* W; const float* bias; unsigned short* out;
    if (which == 0)      { x = q; W = Wq; bias = bq; out = qh; }
    else if (which == 1) { x = k; W = Wk; bias = bk; out = kh; }
    else                 { x = v; W = Wv; bias = bv; out = vh; }

    __shared__ float xs[EMBED];
    __shared__ float Wt[DH][DH + 4];      // Wt[j][d] = W[d*DH + j]

    const int t = threadIdx.x;

    ((float4*)xs)[t] = ((const float4*)(x + (size_t)bs * EMBED))[t];
#pragma unroll
    for (int u = 0; u < 16; ++u) {
        int idx = t * 16 + u;
        Wt[idx & 63][idx >> 6] = W[idx];
    }
    __syncthreads();

    const int lane = t & 63;              // output dim d
    const int wave = t >> 6;              // h = wave + 4*kk

    float acc0 = 0.f, acc1 = 0.f, acc2 = 0.f, acc3 = 0.f;
#pragma unroll
    for (int j = 0; j < DH; ++j) {
        float w = Wt[j][lane];
        acc0 += xs[(wave +  0) * DH + j] * w;
        acc1 += xs[(wave +  4) * DH + j] * w;
        acc2 += xs[(wave +  8) * DH + j] * w;
        acc3 += xs[(wave + 12) * DH + j] * w;
    }
    const int b = bs / SEQ, s = bs % SEQ;
    const float bb = bias[lane];
    out[(((size_t)b * HEADS + (wave +  0)) * SEQ + s) * DH + lane] = f2bf(acc0 + bb);
    out[(((size_t)b * HEADS + (wave +  4)) * SEQ + s) * DH + lane] = f2bf(acc1 + bb);
    out[(((size_t)b * HEADS + (wave +  8)) * SEQ + s) * DH + lane] = f2bf(acc2 + bb);
    out[(((size_t)b * HEADS + (wave + 12)) * SEQ + s) * DH + lane] = f2bf(acc3 + bb);
}

// ---------------------------------------------------------------------------
// Kernel 2: transpose V per head: vh [BH][S][64] -> vt [BH][64][S]  (bf16)
// ---------------------------------------------------------------------------
__global__ __launch_bounds__(256) void vtrans_kernel(
    const unsigned short* __restrict__ vh, unsigned short* __restrict__ vt)
{
    const int st = blockIdx.x;
    const int bh = blockIdx.y;
    __shared__ unsigned short Tt[64 * 72];

    const int t = threadIdx.x;
    const int r = t >> 2, p = t & 3;

    const unsigned short* src = vh + ((size_t)bh * SEQ + st * 64 + r) * DH + p * 16;
    *(uint4*)&Tt[r * 72 + p * 16]     = *(const uint4*)src;
    *(uint4*)&Tt[r * 72 + p * 16 + 8] = *(const uint4*)(src + 8);
    __syncthreads();

    union { unsigned short u[16]; uint4 v[2]; } o;
#pragma unroll
    for (int u = 0; u < 16; ++u) o.u[u] = Tt[(p * 16 + u) * 72 + r];
    unsigned short* dst = vt + ((size_t)bh * DH + r) * SEQ + st * 64 + p * 16;
    *(uint4*)dst       = o.v[0];
    *(uint4*)(dst + 8) = o.v[1];
}

// ---------------------------------------------------------------------------
// Kernel 3: pack int32 mask [B,1,S,S] into bitmask [B, S, S/64] (u64)
// ---------------------------------------------------------------------------
__global__ __launch_bounds__(256) void maskpack_kernel(
    const int* __restrict__ mask, u64* __restrict__ bits)
{
    const int idx = blockIdx.x * 256 + threadIdx.x;   // word index
    const int4* src = (const int4*)(mask + (size_t)idx * 64);
    u64 w = 0;
#pragma unroll
    for (int u = 0; u < 16; ++u) {
        int4 m = src[u];
        u64 nib = (m.x != 0 ? 1ull : 0) | (m.y != 0 ? 2ull : 0) |
                  (m.z != 0 ? 4ull : 0) | (m.w != 0 ? 8ull : 0);
        w |= nib << (u * 4);
    }
    bits[idx] = w;
}

// ---------------------------------------------------------------------------
// Kernel 4: cast Wo (fp32 [1024][1024]) -> bf16
// ---------------------------------------------------------------------------
__global__ __launch_bounds__(256) void wcvt_kernel(
    const float* __restrict__ Wo, unsigned short* __restrict__ Wob)
{
    const int i = (blockIdx.x * 256 + threadIdx.x) * 8;
    float4 a = ((const float4*)(Wo + i))[0];
    float4 b = ((const float4*)(Wo + i))[1];
    unsigned short o[8] = {f2bf(a.x), f2bf(a.y), f2bf(a.z), f2bf(a.w),
                           f2bf(b.x), f2bf(b.y), f2bf(b.z), f2bf(b.w)};
    *(uint4*)(Wob + i) = *(uint4*)o;
}

// ---------------------------------------------------------------------------
// Kernel 5: MFMA flash attention (fixed-max softmax, bf16 in / fp32 accum).
// grid = (SEQ/64, BATCH*HEADS), block = 256. ctx output is bf16 [BH][S][64].
// ---------------------------------------------------------------------------
__global__ __launch_bounds__(256) void attn_kernel(
    const unsigned short* __restrict__ qh, const unsigned short* __restrict__ kh,
    const unsigned short* __restrict__ vt, const u64* __restrict__ mbits,
    unsigned short* __restrict__ ctx)
{
    const int q0 = blockIdx.x * 64;
    const int bh = blockIdx.y;
    const int b  = bh >> 4;

    __shared__ unsigned short Kt[64 * 72];       // [j][d]
    __shared__ unsigned short Vt[64 * 72];       // [d][j]
    __shared__ unsigned short Pt[4 * 16 * 72];   // per-wave [i][j]

    const int t    = threadIdx.x;
    const int w    = t >> 6;
    const int lane = t & 63;
    const int l15  = lane & 15;
    const int quad = lane >> 4;

    bf16x8 qf0, qf1;
    {
        const unsigned short* qb =
            qh + ((size_t)bh * SEQ + q0 + w * 16 + l15) * DH + quad * 8;
        qf0 = *(const bf16x8*)qb;
        qf1 = *(const bf16x8*)(qb + 32);
    }

    f32x4 O[4] = {f32x4{0,0,0,0}, f32x4{0,0,0,0}, f32x4{0,0,0,0}, f32x4{0,0,0,0}};
    float lsum[4] = {0.f, 0.f, 0.f, 0.f};

    const unsigned short* kbase = kh + (size_t)bh * SEQ * DH;
    const unsigned short* vbase = vt + (size_t)bh * DH * SEQ;
    const u64* mbase = mbits + ((size_t)b * SEQ + q0 + w * 16) * (SEQ / 64);

    const int sr = t >> 2, sp = t & 3;

    for (int kt = 0; kt < SEQ / 64; ++kt) {
        __syncthreads();
        {
            const unsigned short* ks = kbase + ((size_t)(kt * 64 + sr)) * DH + sp * 16;
            *(uint4*)&Kt[sr * 72 + sp * 16]     = *(const uint4*)ks;
            *(uint4*)&Kt[sr * 72 + sp * 16 + 8] = *(const uint4*)(ks + 8);
            const unsigned short* vs = vbase + (size_t)sr * SEQ + kt * 64 + sp * 16;
            *(uint4*)&Vt[sr * 72 + sp * 16]     = *(const uint4*)vs;
            *(uint4*)&Vt[sr * 72 + sp * 16 + 8] = *(const uint4*)(vs + 8);
        }
        __syncthreads();

        // ---- QK^T ----
        f32x4 s[4];
#pragma unroll
        for (int st = 0; st < 4; ++st) {
            bf16x8 kf0 = *(const bf16x8*)&Kt[(st * 16 + l15) * 72 + quad * 8];
            bf16x8 kf1 = *(const bf16x8*)&Kt[(st * 16 + l15) * 72 + 32 + quad * 8];
            f32x4 acc = {0, 0, 0, 0};
            acc = __builtin_amdgcn_mfma_f32_16x16x32_bf16(qf0, kf0, acc, 0, 0, 0);
            acc = __builtin_amdgcn_mfma_f32_16x16x32_bf16(qf1, kf1, acc, 0, 0, 0);
            s[st] = acc;
        }

        // ---- mask + exp + pack P to LDS ----
        u64 rb0 = mbase[(quad * 4 + 0) * (SEQ / 64) + kt];
        u64 rb1 = mbase[(quad * 4 + 1) * (SEQ / 64) + kt];
        u64 rb2 = mbase[(quad * 4 + 2) * (SEQ / 64) + kt];
        u64 rb3 = mbase[(quad * 4 + 3) * (SEQ / 64) + kt];
#pragma unroll
        for (int st = 0; st < 4; ++st) {
            const int bitpos = st * 16 + l15;
            float p0 = ((rb0 >> bitpos) & 1ull) ? __expf(fminf(s[st][0] * 0.125f, 60.f)) : 0.f;
            float p1 = ((rb1 >> bitpos) & 1ull) ? __expf(fminf(s[st][1] * 0.125f, 60.f)) : 0.f;
            float p2 = ((rb2 >> bitpos) & 1ull) ? __expf(fminf(s[st][2] * 0.125f, 60.f)) : 0.f;
            float p3 = ((rb3 >> bitpos) & 1ull) ? __expf(fminf(s[st][3] * 0.125f, 60.f)) : 0.f;
            lsum[0] += p0; lsum[1] += p1; lsum[2] += p2; lsum[3] += p3;
            const int col = st * 16 + l15;
            Pt[(w * 16 + quad * 4 + 0) * 72 + col] = f2bf(p0);
            Pt[(w * 16 + quad * 4 + 1) * 72 + col] = f2bf(p1);
            Pt[(w * 16 + quad * 4 + 2) * 72 + col] = f2bf(p2);
            Pt[(w * 16 + quad * 4 + 3) * 72 + col] = f2bf(p3);
        }
        __threadfence_block();

        // ---- PV ----
#pragma unroll
        for (int jc = 0; jc < 2; ++jc) {
            bf16x8 pf = *(const bf16x8*)&Pt[(w * 16 + l15) * 72 + jc * 32 + quad * 8];
#pragma unroll
            for (int st = 0; st < 4; ++st) {
                bf16x8 vf = *(const bf16x8*)&Vt[(st * 16 + l15) * 72 + jc * 32 + quad * 8];
                O[st] = __builtin_amdgcn_mfma_f32_16x16x32_bf16(pf, vf, O[st], 0, 0, 0);
            }
        }
    }

#pragma unroll
    for (int r = 0; r < 4; ++r) {
        float lr = lsum[r];
        lr += __shfl_xor(lr, 1);
        lr += __shfl_xor(lr, 2);
        lr += __shfl_xor(lr, 4);
        lr += __shfl_xor(lr, 8);
        const float inv = 1.0f / lr;
        unsigned short* dst = ctx + ((size_t)bh * SEQ + q0 + w * 16 + quad * 4 + r) * DH + l15;
        dst[0]  = f2bf(O[0][r] * inv);
        dst[16] = f2bf(O[1][r] * inv);
        dst[32] = f2bf(O[2][r] * inv);
        dst[48] = f2bf(O[3][r] * inv);
    }
}

// ---------------------------------------------------------------------------
// Kernel 6: output projection via MFMA.
// out[m,n] = sum_k ctx[m,k]*Wo[n,k] + bo[n]; ctx bf16 [B,H,S,64], Wo bf16 [n][k].
// grid = (N/64=16, M/64=64), block = 256 (4 waves; wave w owns n-stripe w*16).
// BK = 64 = one head slice -> contiguous A-tile rows.
// ---------------------------------------------------------------------------
__global__ __launch_bounds__(256) void outproj_mfma(
    const unsigned short* __restrict__ ctx, const unsigned short* __restrict__ Wob,
    const float* __restrict__ bo, float* __restrict__ out)
{
    const int n0 = blockIdx.x * 64;
    const int m0 = blockIdx.y * 64;
    const int b  = m0 / SEQ;
    const int s0 = m0 % SEQ;

    __shared__ unsigned short At[64 * 72];
    __shared__ unsigned short Wt[64 * 72];

    const int t    = threadIdx.x;
    const int w    = t >> 6;
    const int lane = t & 63;
    const int l15  = lane & 15;
    const int quad = lane >> 4;
    const int sr = t >> 2, sp = t & 3;

    f32x4 acc[4] = {f32x4{0,0,0,0}, f32x4{0,0,0,0}, f32x4{0,0,0,0}, f32x4{0,0,0,0}};

    for (int kt = 0; kt < HEADS; ++kt) {
        __syncthreads();
        {
            const unsigned short* as =
                ctx + (((size_t)b * HEADS + kt) * SEQ + s0 + sr) * DH + sp * 16;
            *(uint4*)&At[sr * 72 + sp * 16]     = *(const uint4*)as;
            *(uint4*)&At[sr * 72 + sp * 16 + 8] = *(const uint4*)(as + 8);
            const unsigned short* wsrc =
                Wob + (size_t)(n0 + sr) * EMBED + kt * 64 + sp * 16;
            *(uint4*)&Wt[sr * 72 + sp * 16]     = *(const uint4*)wsrc;
            *(uint4*)&Wt[sr * 72 + sp * 16 + 8] = *(const uint4*)(wsrc + 8);
        }
        __syncthreads();

        bf16x8 bf0 = *(const bf16x8*)&Wt[(w * 16 + l15) * 72 + quad * 8];
        bf16x8 bf1 = *(const bf16x8*)&Wt[(w * 16 + l15) * 72 + 32 + quad * 8];
#pragma unroll
        for (int mt = 0; mt < 4; ++mt) {
            bf16x8 af0 = *(const bf16x8*)&At[(mt * 16 + l15) * 72 + quad * 8];
            bf16x8 af1 = *(const bf16x8*)&At[(mt * 16 + l15) * 72 + 32 + quad * 8];
            acc[mt] = __builtin_amdgcn_mfma_f32_16x16x32_bf16(af0, bf0, acc[mt], 0, 0, 0);
            acc[mt] = __builtin_amdgcn_mfma_f32_16x16x32_bf16(af1, bf1, acc[mt], 0, 0, 0);
        }
    }

    const float bv = bo[n0 + w * 16 + l15];
#pragma unroll
    for (int mt = 0; mt < 4; ++mt) {
#pragma unroll
        for (int r = 0; r < 4; ++r) {
            out[(size_t)(m0 + mt * 16 + quad * 4 + r) * EMBED + n0 + w * 16 + l15] =
                acc[mt][r] + bv;
        }
    }
}

// ---------------------------------------------------------------------------
extern "C" void kernel_launch(void* const* d_in, const int* in_sizes, int n_in,
                              void* d_out, int out_size, void* d_ws, size_t ws_size,
                              hipStream_t stream) {
    const float* k    = (const float*)d_in[0];
    const float* q    = (const float*)d_in[1];
    const float* v    = (const float*)d_in[2];
    const int*   mask = (const int*)  d_in[3];
    const float* Wk   = (const float*)d_in[4];
    const float* bk   = (const float*)d_in[5];
    const float* Wq   = (const float*)d_in[6];
    const float* bq   = (const float*)d_in[7];
    const float* Wv   = (const float*)d_in[8];
    const float* bv   = (const float*)d_in[9];
    const float* Wo   = (const float*)d_in[10];
    const float* bo   = (const float*)d_in[11];
    float* out = (float*)d_out;

    const size_t TEN = (size_t)BATCH * HEADS * SEQ * DH;   // 4,194,304 elems
    unsigned short* qh_bf = (unsigned short*)d_ws;         // 8 MB
    unsigned short* kh_bf = qh_bf + TEN;                   // 8 MB
    unsigned short* vh_bf = kh_bf + TEN;                   // 8 MB
    unsigned short* vt_bf = vh_bf + TEN;                   // 8 MB
    unsigned short* ctxb  = vt_bf + TEN;                   // 8 MB
    unsigned short* Wob   = ctxb + TEN;                    // 2 MB
    u64*            mbits = (u64*)(Wob + EMBED * EMBED);   // 1 MB  (43 MB total)

    proj_kernel<<<dim3(BATCH * SEQ, 3), 256, 0, stream>>>(
        q, k, v, Wq, bq, Wk, bk, Wv, bv, qh_bf, kh_bf, vh_bf);
    vtrans_kernel<<<dim3(SEQ / 64, BATCH * HEADS), 256, 0, stream>>>(vh_bf, vt_bf);
    maskpack_kernel<<<dim3((BATCH * SEQ * (SEQ / 64)) / 256), 256, 0, stream>>>(mask, mbits);
    wcvt_kernel<<<dim3(EMBED * EMBED / (256 * 8)), 256, 0, stream>>>(Wo, Wob);
    attn_kernel<<<dim3(SEQ / 64, BATCH * HEADS), 256, 0, stream>>>(
        qh_bf, kh_bf, vt_bf, mbits, ctxb);
    outproj_mfma<<<dim3(EMBED / 64, BATCH * SEQ / 64), 256, 0, stream>>>(
        ctxb, Wob, bo, out);
}

// Round 5
// 260.946 us; speedup vs baseline: 5.9764x; 1.0934x over previous
//
#include <hip/hip_runtime.h>
#include <hip/hip_bf16.h>
#include <math.h>

#define EMBED 1024
#define HEADS 16
#define DH    64
#define BATCH 2
#define SEQ   2048

typedef __attribute__((ext_vector_type(8))) short bf16x8;
typedef __attribute__((ext_vector_type(4))) short bf16x4;
typedef __attribute__((ext_vector_type(4))) float f32x4;
typedef unsigned long long u64;

static __device__ __forceinline__ unsigned short f2bf(float x) {
    unsigned u = __builtin_bit_cast(unsigned, x);
    return (unsigned short)((u + 0x7fffu + ((u >> 16) & 1u)) >> 16);
}

// ---------------------------------------------------------------------------
// Kernel 1: QKV projection via MFMA.  X viewed as [M=B*S*H][64] (row m =
// (b*S+s)*H + h since EMBED = H*DH is contiguous), Y[m][n] = sum_k X[m][k] *
// W[n][k] + b[n], written bf16 to [B,H,S,DH].
// grid = (M/64 = 1024, 3), block = 256. Wave w owns 16 rows = one (b,s)
// (all 16 heads); 4 N-tiles cover the 64 output dims.
// ---------------------------------------------------------------------------
__global__ __launch_bounds__(256) void proj_mfma(
    const float* __restrict__ q, const float* __restrict__ k, const float* __restrict__ v,
    const float* __restrict__ Wq, const float* __restrict__ bq,
    const float* __restrict__ Wk, const float* __restrict__ bk,
    const float* __restrict__ Wv, const float* __restrict__ bv,
    unsigned short* __restrict__ qh, unsigned short* __restrict__ kh,
    unsigned short* __restrict__ vh)
{
    const int blk = blockIdx.x;           // 0..1023
    const int which = blockIdx.y;
    const float* x; const float* W; const float* bias; unsigned short* out;
    if (which == 0)      { x = q; W = Wq; bias = bq; out = qh; }
    else if (which == 1) { x = k; W = Wk; bias = bk; out = kh; }
    else                 { x = v; W = Wv; bias = bv; out = vh; }

    __shared__ unsigned short Xs[64 * 72];
    __shared__ unsigned short Ws[64 * 72];

    const int t  = threadIdx.x;
    const int sr = t >> 2, sp = t & 3;

    // stage X tile (64 rows x 64 k, fp32 -> bf16) and W ([n][k] natural)
    {
        const float* xsrc = x + ((size_t)blk * 64 + sr) * 64 + sp * 16;
        unsigned short o[16];
#pragma unroll
        for (int u4 = 0; u4 < 4; ++u4) {
            float4 a = ((const float4*)xsrc)[u4];
            o[u4*4+0] = f2bf(a.x); o[u4*4+1] = f2bf(a.y);
            o[u4*4+2] = f2bf(a.z); o[u4*4+3] = f2bf(a.w);
        }
        *(uint4*)&Xs[sr * 72 + sp * 16]     = *(uint4*)&o[0];
        *(uint4*)&Xs[sr * 72 + sp * 16 + 8] = *(uint4*)&o[8];
        const float* wsrc = W + (size_t)sr * 64 + sp * 16;
        unsigned short wo[16];
#pragma unroll
        for (int u4 = 0; u4 < 4; ++u4) {
            float4 a = ((const float4*)wsrc)[u4];
            wo[u4*4+0] = f2bf(a.x); wo[u4*4+1] = f2bf(a.y);
            wo[u4*4+2] = f2bf(a.z); wo[u4*4+3] = f2bf(a.w);
        }
        *(uint4*)&Ws[sr * 72 + sp * 16]     = *(uint4*)&wo[0];
        *(uint4*)&Ws[sr * 72 + sp * 16 + 8] = *(uint4*)&wo[8];
    }
    __syncthreads();

    const int w    = t >> 6;
    const int lane = t & 63;
    const int l15  = lane & 15;
    const int quad = lane >> 4;

    bf16x8 af0 = *(const bf16x8*)&Xs[(w * 16 + l15) * 72 + quad * 8];
    bf16x8 af1 = *(const bf16x8*)&Xs[(w * 16 + l15) * 72 + 32 + quad * 8];

    f32x4 acc[4];
#pragma unroll
    for (int nt = 0; nt < 4; ++nt) {
        bf16x8 bf0 = *(const bf16x8*)&Ws[(nt * 16 + l15) * 72 + quad * 8];
        bf16x8 bf1 = *(const bf16x8*)&Ws[(nt * 16 + l15) * 72 + 32 + quad * 8];
        f32x4 a = {0, 0, 0, 0};
        a = __builtin_amdgcn_mfma_f32_16x16x32_bf16(af0, bf0, a, 0, 0, 0);
        a = __builtin_amdgcn_mfma_f32_16x16x32_bf16(af1, bf1, a, 0, 0, 0);
        acc[nt] = a;
    }

    // row m = blk*64 + w*16 + quad*4 + r = (b*S+s)*16 + h ; col d = nt*16+l15
    const int bsidx = blk * 4 + w;
    const int b = bsidx >> 11, s = bsidx & 2047;
#pragma unroll
    for (int nt = 0; nt < 4; ++nt) {
        const int d = nt * 16 + l15;
        const float bb = bias[d];
#pragma unroll
        for (int r = 0; r < 4; ++r) {
            const int h = quad * 4 + r;
            out[(((size_t)b * HEADS + h) * SEQ + s) * DH + d] = f2bf(acc[nt][r] + bb);
        }
    }
}

// ---------------------------------------------------------------------------
// Kernel 2: transpose V per head: vh [BH][S][64] -> vt [BH][64][S]  (bf16)
// ---------------------------------------------------------------------------
__global__ __launch_bounds__(256) void vtrans_kernel(
    const unsigned short* __restrict__ vh, unsigned short* __restrict__ vt)
{
    const int st = blockIdx.x;
    const int bh = blockIdx.y;
    __shared__ unsigned short Tt[64 * 72];

    const int t = threadIdx.x;
    const int r = t >> 2, p = t & 3;

    const unsigned short* src = vh + ((size_t)bh * SEQ + st * 64 + r) * DH + p * 16;
    *(uint4*)&Tt[r * 72 + p * 16]     = *(const uint4*)src;
    *(uint4*)&Tt[r * 72 + p * 16 + 8] = *(const uint4*)(src + 8);
    __syncthreads();

    union { unsigned short u[16]; uint4 v[2]; } o;
#pragma unroll
    for (int u = 0; u < 16; ++u) o.u[u] = Tt[(p * 16 + u) * 72 + r];
    unsigned short* dst = vt + ((size_t)bh * DH + r) * SEQ + st * 64 + p * 16;
    *(uint4*)dst       = o.v[0];
    *(uint4*)(dst + 8) = o.v[1];
}

// ---------------------------------------------------------------------------
// Kernel 3: pack int32 mask [B,1,S,S] into bitmask [B, S, S/64] (u64)
// ---------------------------------------------------------------------------
__global__ __launch_bounds__(256) void maskpack_kernel(
    const int* __restrict__ mask, u64* __restrict__ bits)
{
    const int idx = blockIdx.x * 256 + threadIdx.x;   // word index
    const int4* src = (const int4*)(mask + (size_t)idx * 64);
    u64 w = 0;
#pragma unroll
    for (int u = 0; u < 16; ++u) {
        int4 m = src[u];
        u64 nib = (m.x != 0 ? 1ull : 0) | (m.y != 0 ? 2ull : 0) |
                  (m.z != 0 ? 4ull : 0) | (m.w != 0 ? 8ull : 0);
        w |= nib << (u * 4);
    }
    bits[idx] = w;
}

// ---------------------------------------------------------------------------
// Kernel 4: cast Wo (fp32 [1024][1024]) -> bf16
// ---------------------------------------------------------------------------
__global__ __launch_bounds__(256) void wcvt_kernel(
    const float* __restrict__ Wo, unsigned short* __restrict__ Wob)
{
    const int i = (blockIdx.x * 256 + threadIdx.x) * 8;
    float4 a = ((const float4*)(Wo + i))[0];
    float4 b = ((const float4*)(Wo + i))[1];
    unsigned short o[8] = {f2bf(a.x), f2bf(a.y), f2bf(a.z), f2bf(a.w),
                           f2bf(b.x), f2bf(b.y), f2bf(b.z), f2bf(b.w)};
    *(uint4*)(Wob + i) = *(uint4*)o;
}

// ---------------------------------------------------------------------------
// Kernel 5: MFMA flash attention, transposed-score formulation.
// S^T = K*Q^T via mfma(kf, qf): lane (l15,quad) reg r holds
// S[i=l15][j=st*16+quad*4+r] -- exactly the A-fragment layout of
// mfma_f32_16x16x16bf16_1k, so P feeds PV straight from registers.
// 32 Q rows per wave, 128 per block. grid = (SEQ/128, BATCH*HEADS).
// ---------------------------------------------------------------------------
__global__ __launch_bounds__(256) void attn_kernel(
    const unsigned short* __restrict__ qh, const unsigned short* __restrict__ kh,
    const unsigned short* __restrict__ vt, const u64* __restrict__ mbits,
    unsigned short* __restrict__ ctx)
{
    const int q0 = blockIdx.x * 128;
    const int bh = blockIdx.y;
    const int b  = bh >> 4;

    __shared__ unsigned short Kt[64 * 72];       // [j][d]
    __shared__ unsigned short Vt[64 * 72];       // [d][j]

    const int t    = threadIdx.x;
    const int w    = t >> 6;
    const int lane = t & 63;
    const int l15  = lane & 15;
    const int quad = lane >> 4;
    const int sr = t >> 2, sp = t & 3;

    // Q fragments for two 16-row groups, held in registers for the whole loop
    bf16x8 qf[2][2];
#pragma unroll
    for (int g = 0; g < 2; ++g) {
        const unsigned short* qb =
            qh + ((size_t)bh * SEQ + q0 + w * 32 + g * 16 + l15) * DH + quad * 8;
        qf[g][0] = *(const bf16x8*)qb;
        qf[g][1] = *(const bf16x8*)(qb + 32);
    }

    f32x4 O[2][4];
#pragma unroll
    for (int g = 0; g < 2; ++g)
#pragma unroll
        for (int dt = 0; dt < 4; ++dt) O[g][dt] = f32x4{0, 0, 0, 0};
    float lsum[2] = {0.f, 0.f};

    const unsigned short* kbase = kh + (size_t)bh * SEQ * DH;
    const unsigned short* vbase = vt + (size_t)bh * DH * SEQ;
    const u64* mrow0 = mbits + ((size_t)b * SEQ + q0 + w * 32 + l15) * (SEQ / 64);
    const u64* mrow1 = mrow0 + 16 * (SEQ / 64);

    for (int kt = 0; kt < SEQ / 64; ++kt) {
        __syncthreads();
        {
            const unsigned short* ks = kbase + ((size_t)(kt * 64 + sr)) * DH + sp * 16;
            *(uint4*)&Kt[sr * 72 + sp * 16]     = *(const uint4*)ks;
            *(uint4*)&Kt[sr * 72 + sp * 16 + 8] = *(const uint4*)(ks + 8);
            const unsigned short* vs = vbase + (size_t)sr * SEQ + kt * 64 + sp * 16;
            *(uint4*)&Vt[sr * 72 + sp * 16]     = *(const uint4*)vs;
            *(uint4*)&Vt[sr * 72 + sp * 16 + 8] = *(const uint4*)(vs + 8);
        }
        const u64 mb0 = mrow0[kt];
        const u64 mb1 = mrow1[kt];
        __syncthreads();

        // ---- S^T tiles + masked exp; P stays in registers ----
        bf16x4 p[2][4];
#pragma unroll
        for (int st = 0; st < 4; ++st) {
            bf16x8 kf0 = *(const bf16x8*)&Kt[(st * 16 + l15) * 72 + quad * 8];
            bf16x8 kf1 = *(const bf16x8*)&Kt[(st * 16 + l15) * 72 + 32 + quad * 8];
#pragma unroll
            for (int g = 0; g < 2; ++g) {
                f32x4 sa = {0, 0, 0, 0};
                sa = __builtin_amdgcn_mfma_f32_16x16x32_bf16(kf0, qf[g][0], sa, 0, 0, 0);
                sa = __builtin_amdgcn_mfma_f32_16x16x32_bf16(kf1, qf[g][1], sa, 0, 0, 0);
                const u64 mb = g ? mb1 : mb0;
                const int bp = st * 16 + quad * 4;
                float p0 = ((mb >> (bp + 0)) & 1ull) ? __expf(fminf(sa[0] * 0.125f, 60.f)) : 0.f;
                float p1 = ((mb >> (bp + 1)) & 1ull) ? __expf(fminf(sa[1] * 0.125f, 60.f)) : 0.f;
                float p2 = ((mb >> (bp + 2)) & 1ull) ? __expf(fminf(sa[2] * 0.125f, 60.f)) : 0.f;
                float p3 = ((mb >> (bp + 3)) & 1ull) ? __expf(fminf(sa[3] * 0.125f, 60.f)) : 0.f;
                lsum[g] += (p0 + p1) + (p2 + p3);
                union { __hip_bfloat162 h2[2]; bf16x4 v; } pu;
                pu.h2[0] = __float22bfloat162_rn(make_float2(p0, p1));
                pu.h2[1] = __float22bfloat162_rn(make_float2(p2, p3));
                p[g][st] = pu.v;
            }
        }

        // ---- PV: O[g][dt] += P * V (K=16 MFMA, B-frags straight from Vt) ----
#pragma unroll
        for (int dt = 0; dt < 4; ++dt) {
#pragma unroll
            for (int st = 0; st < 4; ++st) {
                bf16x4 vb = *(const bf16x4*)&Vt[(dt * 16 + l15) * 72 + st * 16 + quad * 4];
                O[0][dt] = __builtin_amdgcn_mfma_f32_16x16x16bf16_1k(p[0][st], vb, O[0][dt], 0, 0, 0);
                O[1][dt] = __builtin_amdgcn_mfma_f32_16x16x16bf16_1k(p[1][st], vb, O[1][dt], 0, 0, 0);
            }
        }
    }

    // ---- epilogue: reduce row sums across quads, normalize, store bf16 ----
#pragma unroll
    for (int g = 0; g < 2; ++g) {
        float lr = lsum[g];
        lr += __shfl_xor(lr, 16);
        lr += __shfl_xor(lr, 32);               // row (g,l15) total in every lane
        const float invl = 1.0f / lr;
        float invr[4];
#pragma unroll
        for (int r = 0; r < 4; ++r) invr[r] = __shfl(invl, quad * 4 + r);
        const size_t rbase = (size_t)bh * SEQ + q0 + w * 32 + g * 16 + quad * 4;
#pragma unroll
        for (int r = 0; r < 4; ++r) {
            unsigned short* dst = ctx + (rbase + r) * DH + l15;
            dst[0]  = f2bf(O[g][0][r] * invr[r]);
            dst[16] = f2bf(O[g][1][r] * invr[r]);
            dst[32] = f2bf(O[g][2][r] * invr[r]);
            dst[48] = f2bf(O[g][3][r] * invr[r]);
        }
    }
}

// ---------------------------------------------------------------------------
// Kernel 6: output projection via MFMA (verified in R3).
// ---------------------------------------------------------------------------
__global__ __launch_bounds__(256) void outproj_mfma(
    const unsigned short* __restrict__ ctx, const unsigned short* __restrict__ Wob,
    const float* __restrict__ bo, float* __restrict__ out)
{
    const int n0 = blockIdx.x * 64;
    const int m0 = blockIdx.y * 64;
    const int b  = m0 / SEQ;
    const int s0 = m0 % SEQ;

    __shared__ unsigned short At[64 * 72];
    __shared__ unsigned short Wt[64 * 72];

    const int t    = threadIdx.x;
    const int w    = t >> 6;
    const int lane = t & 63;
    const int l15  = lane & 15;
    const int quad = lane >> 4;
    const int sr = t >> 2, sp = t & 3;

    f32x4 acc[4] = {f32x4{0,0,0,0}, f32x4{0,0,0,0}, f32x4{0,0,0,0}, f32x4{0,0,0,0}};

    for (int kt = 0; kt < HEADS; ++kt) {
        __syncthreads();
        {
            const unsigned short* as =
                ctx + (((size_t)b * HEADS + kt) * SEQ + s0 + sr) * DH + sp * 16;
            *(uint4*)&At[sr * 72 + sp * 16]     = *(const uint4*)as;
            *(uint4*)&At[sr * 72 + sp * 16 + 8] = *(const uint4*)(as + 8);
            const unsigned short* wsrc =
                Wob + (size_t)(n0 + sr) * EMBED + kt * 64 + sp * 16;
            *(uint4*)&Wt[sr * 72 + sp * 16]     = *(const uint4*)wsrc;
            *(uint4*)&Wt[sr * 72 + sp * 16 + 8] = *(const uint4*)(wsrc + 8);
        }
        __syncthreads();

        bf16x8 bf0 = *(const bf16x8*)&Wt[(w * 16 + l15) * 72 + quad * 8];
        bf16x8 bf1 = *(const bf16x8*)&Wt[(w * 16 + l15) * 72 + 32 + quad * 8];
#pragma unroll
        for (int mt = 0; mt < 4; ++mt) {
            bf16x8 af0 = *(const bf16x8*)&At[(mt * 16 + l15) * 72 + quad * 8];
            bf16x8 af1 = *(const bf16x8*)&At[(mt * 16 + l15) * 72 + 32 + quad * 8];
            acc[mt] = __builtin_amdgcn_mfma_f32_16x16x32_bf16(af0, bf0, acc[mt], 0, 0, 0);
            acc[mt] = __builtin_amdgcn_mfma_f32_16x16x32_bf16(af1, bf1, acc[mt], 0, 0, 0);
        }
    }

    const float bv = bo[n0 + w * 16 + l15];
#pragma unroll
    for (int mt = 0; mt < 4; ++mt) {
#pragma unroll
        for (int r = 0; r < 4; ++r) {
            out[(size_t)(m0 + mt * 16 + quad * 4 + r) * EMBED + n0 + w * 16 + l15] =
                acc[mt][r] + bv;
        }
    }
}

// ---------------------------------------------------------------------------
extern "C" void kernel_launch(void* const* d_in, const int* in_sizes, int n_in,
                              void* d_out, int out_size, void* d_ws, size_t ws_size,
                              hipStream_t stream) {
    const float* k    = (const float*)d_in[0];
    const float* q    = (const float*)d_in[1];
    const float* v    = (const float*)d_in[2];
    const int*   mask = (const int*)  d_in[3];
    const float* Wk   = (const float*)d_in[4];
    const float* bk   = (const float*)d_in[5];
    const float* Wq   = (const float*)d_in[6];
    const float* bq   = (const float*)d_in[7];
    const float* Wv   = (const float*)d_in[8];
    const float* bv   = (const float*)d_in[9];
    const float* Wo   = (const float*)d_in[10];
    const float* bo   = (const float*)d_in[11];
    float* out = (float*)d_out;

    const size_t TEN = (size_t)BATCH * HEADS * SEQ * DH;   // 4,194,304 elems
    unsigned short* qh_bf = (unsigned short*)d_ws;         // 8 MB
    unsigned short* kh_bf = qh_bf + TEN;                   // 8 MB
    unsigned short* vh_bf = kh_bf + TEN;                   // 8 MB
    unsigned short* vt_bf = vh_bf + TEN;                   // 8 MB
    unsigned short* ctxb  = vt_bf + TEN;                   // 8 MB
    unsigned short* Wob   = ctxb + TEN;                    // 2 MB
    u64*            mbits = (u64*)(Wob + EMBED * EMBED);   // 1 MB  (43 MB total)

    proj_mfma<<<dim3(BATCH * SEQ * HEADS / 64, 3), 256, 0, stream>>>(
        q, k, v, Wq, bq, Wk, bk, Wv, bv, qh_bf, kh_bf, vh_bf);
    vtrans_kernel<<<dim3(SEQ / 64, BATCH * HEADS), 256, 0, stream>>>(vh_bf, vt_bf);
    maskpack_kernel<<<dim3((BATCH * SEQ * (SEQ / 64)) / 256), 256, 0, stream>>>(mask, mbits);
    wcvt_kernel<<<dim3(EMBED * EMBED / (256 * 8)), 256, 0, stream>>>(Wo, Wob);
    attn_kernel<<<dim3(SEQ / 128, BATCH * HEADS), 256, 0, stream>>>(
        qh_bf, kh_bf, vt_bf, mbits, ctxb);
    outproj_mfma<<<dim3(EMBED / 64, BATCH * SEQ / 64), 256, 0, stream>>>(
        ctxb, Wob, bo, out);
}

// Round 6
// 254.955 us; speedup vs baseline: 6.1168x; 1.0235x over previous
//
#include <hip/hip_runtime.h>
#include <hip/hip_bf16.h>
#include <math.h>

#define EMBED 1024
#define HEADS 16
#define DH    64
#define BATCH 2
#define SEQ   2048

typedef __attribute__((ext_vector_type(8))) short bf16x8;
typedef __attribute__((ext_vector_type(4))) short bf16x4;
typedef __attribute__((ext_vector_type(4))) float f32x4;
typedef unsigned long long u64;

static __device__ __forceinline__ unsigned short f2bf(float x) {
    unsigned u = __builtin_bit_cast(unsigned, x);
    return (unsigned short)((u + 0x7fffu + ((u >> 16) & 1u)) >> 16);
}

// ---------------------------------------------------------------------------
// Kernel 1: QKV projection via MFMA (verified R5).  X viewed as [M=B*S*H][64],
// Y[m][n] = sum_k X[m][k]*W[n][k] + b[n], written bf16 to [B,H,S,DH].
// grid = (1024, 3), block = 256.
// ---------------------------------------------------------------------------
__global__ __launch_bounds__(256) void proj_mfma(
    const float* __restrict__ q, const float* __restrict__ k, const float* __restrict__ v,
    const float* __restrict__ Wq, const float* __restrict__ bq,
    const float* __restrict__ Wk, const float* __restrict__ bk,
    const float* __restrict__ Wv, const float* __restrict__ bv,
    unsigned short* __restrict__ qh, unsigned short* __restrict__ kh,
    unsigned short* __restrict__ vh)
{
    const int blk = blockIdx.x;           // 0..1023
    const int which = blockIdx.y;
    const float* x; const float* W; const float* bias; unsigned short* out;
    if (which == 0)      { x = q; W = Wq; bias = bq; out = qh; }
    else if (which == 1) { x = k; W = Wk; bias = bk; out = kh; }
    else                 { x = v; W = Wv; bias = bv; out = vh; }

    __shared__ unsigned short Xs[64 * 72];
    __shared__ unsigned short Ws[64 * 72];

    const int t  = threadIdx.x;
    const int sr = t >> 2, sp = t & 3;

    {
        const float* xsrc = x + ((size_t)blk * 64 + sr) * 64 + sp * 16;
        unsigned short o[16];
#pragma unroll
        for (int u4 = 0; u4 < 4; ++u4) {
            float4 a = ((const float4*)xsrc)[u4];
            o[u4*4+0] = f2bf(a.x); o[u4*4+1] = f2bf(a.y);
            o[u4*4+2] = f2bf(a.z); o[u4*4+3] = f2bf(a.w);
        }
        *(uint4*)&Xs[sr * 72 + sp * 16]     = *(uint4*)&o[0];
        *(uint4*)&Xs[sr * 72 + sp * 16 + 8] = *(uint4*)&o[8];
        const float* wsrc = W + (size_t)sr * 64 + sp * 16;
        unsigned short wo[16];
#pragma unroll
        for (int u4 = 0; u4 < 4; ++u4) {
            float4 a = ((const float4*)wsrc)[u4];
            wo[u4*4+0] = f2bf(a.x); wo[u4*4+1] = f2bf(a.y);
            wo[u4*4+2] = f2bf(a.z); wo[u4*4+3] = f2bf(a.w);
        }
        *(uint4*)&Ws[sr * 72 + sp * 16]     = *(uint4*)&wo[0];
        *(uint4*)&Ws[sr * 72 + sp * 16 + 8] = *(uint4*)&wo[8];
    }
    __syncthreads();

    const int w    = t >> 6;
    const int lane = t & 63;
    const int l15  = lane & 15;
    const int quad = lane >> 4;

    bf16x8 af0 = *(const bf16x8*)&Xs[(w * 16 + l15) * 72 + quad * 8];
    bf16x8 af1 = *(const bf16x8*)&Xs[(w * 16 + l15) * 72 + 32 + quad * 8];

    f32x4 acc[4];
#pragma unroll
    for (int nt = 0; nt < 4; ++nt) {
        bf16x8 bf0 = *(const bf16x8*)&Ws[(nt * 16 + l15) * 72 + quad * 8];
        bf16x8 bf1 = *(const bf16x8*)&Ws[(nt * 16 + l15) * 72 + 32 + quad * 8];
        f32x4 a = {0, 0, 0, 0};
        a = __builtin_amdgcn_mfma_f32_16x16x32_bf16(af0, bf0, a, 0, 0, 0);
        a = __builtin_amdgcn_mfma_f32_16x16x32_bf16(af1, bf1, a, 0, 0, 0);
        acc[nt] = a;
    }

    const int bsidx = blk * 4 + w;
    const int b = bsidx >> 11, s = bsidx & 2047;
#pragma unroll
    for (int nt = 0; nt < 4; ++nt) {
        const int d = nt * 16 + l15;
        const float bb = bias[d];
#pragma unroll
        for (int r = 0; r < 4; ++r) {
            const int h = quad * 4 + r;
            out[(((size_t)b * HEADS + h) * SEQ + s) * DH + d] = f2bf(acc[nt][r] + bb);
        }
    }
}

// ---------------------------------------------------------------------------
// Kernel 2: transpose V per head: vh [BH][S][64] -> vt [BH][64][S]  (bf16)
// ---------------------------------------------------------------------------
__global__ __launch_bounds__(256) void vtrans_kernel(
    const unsigned short* __restrict__ vh, unsigned short* __restrict__ vt)
{
    const int st = blockIdx.x;
    const int bh = blockIdx.y;
    __shared__ unsigned short Tt[64 * 72];

    const int t = threadIdx.x;
    const int r = t >> 2, p = t & 3;

    const unsigned short* src = vh + ((size_t)bh * SEQ + st * 64 + r) * DH + p * 16;
    *(uint4*)&Tt[r * 72 + p * 16]     = *(const uint4*)src;
    *(uint4*)&Tt[r * 72 + p * 16 + 8] = *(const uint4*)(src + 8);
    __syncthreads();

    union { unsigned short u[16]; uint4 v[2]; } o;
#pragma unroll
    for (int u = 0; u < 16; ++u) o.u[u] = Tt[(p * 16 + u) * 72 + r];
    unsigned short* dst = vt + ((size_t)bh * DH + r) * SEQ + st * 64 + p * 16;
    *(uint4*)dst       = o.v[0];
    *(uint4*)(dst + 8) = o.v[1];
}

// ---------------------------------------------------------------------------
// Kernel 3: pack int32 mask [B,1,S,S] into bitmask [B, S, S/64] (u64)
// ---------------------------------------------------------------------------
__global__ __launch_bounds__(256) void maskpack_kernel(
    const int* __restrict__ mask, u64* __restrict__ bits)
{
    const int idx = blockIdx.x * 256 + threadIdx.x;
    const int4* src = (const int4*)(mask + (size_t)idx * 64);
    u64 w = 0;
#pragma unroll
    for (int u = 0; u < 16; ++u) {
        int4 m = src[u];
        u64 nib = (m.x != 0 ? 1ull : 0) | (m.y != 0 ? 2ull : 0) |
                  (m.z != 0 ? 4ull : 0) | (m.w != 0 ? 8ull : 0);
        w |= nib << (u * 4);
    }
    bits[idx] = w;
}

// ---------------------------------------------------------------------------
// Kernel 4: cast Wo (fp32 [1024][1024]) -> bf16
// ---------------------------------------------------------------------------
__global__ __launch_bounds__(256) void wcvt_kernel(
    const float* __restrict__ Wo, unsigned short* __restrict__ Wob)
{
    const int i = (blockIdx.x * 256 + threadIdx.x) * 8;
    float4 a = ((const float4*)(Wo + i))[0];
    float4 b = ((const float4*)(Wo + i))[1];
    unsigned short o[8] = {f2bf(a.x), f2bf(a.y), f2bf(a.z), f2bf(a.w),
                           f2bf(b.x), f2bf(b.y), f2bf(b.z), f2bf(b.w)};
    *(uint4*)(Wob + i) = *(uint4*)o;
}

// ---------------------------------------------------------------------------
// Kernel 5: MFMA flash attention, transposed-score + split-K-in-block.
// block = 512 (8 waves): waves 0-3 handle K in [0,1024), waves 4-7 handle
// [1024,2048) over the same 128 Q rows; fixed-max softmax makes the merge a
// pure add (O, lsum) via LDS. Register-prefetch of next K/V/mask tile hides
// global latency. grid = flat 512; bh = bid & 31 -> XCD-local K/V reuse.
// ---------------------------------------------------------------------------
__global__ __launch_bounds__(512, 4) void attn_kernel(
    const unsigned short* __restrict__ qh, const unsigned short* __restrict__ kh,
    const unsigned short* __restrict__ vt, const u64* __restrict__ mbits,
    unsigned short* __restrict__ ctx)
{
    const int bid = blockIdx.x;
    const int bh  = bid & 31;             // all q-tiles of bh -> same XCD set
    const int q0  = (bid >> 5) * 128;
    const int b   = bh >> 4;

    __shared__ uint4 smem4[2304];         // 36864 B, unioned K/V + epilogue
    unsigned short* KtH = ((unsigned short*)smem4) + (threadIdx.x >> 8) * 9216;
    unsigned short* VtH = KtH + 4608;

    const int t    = threadIdx.x;
    const int half = t >> 8;              // K-range half
    const int w    = (t >> 6) & 3;        // wave within half
    const int lane = t & 63;
    const int l15  = lane & 15;
    const int quad = lane >> 4;
    const int t2   = t & 255;
    const int sr   = t2 >> 2, sp = t2 & 3;

    // Q fragments: 32 rows per wave (2 groups), resident all loop
    bf16x8 qf[2][2];
#pragma unroll
    for (int g = 0; g < 2; ++g) {
        const unsigned short* qb =
            qh + ((size_t)bh * SEQ + q0 + w * 32 + g * 16 + l15) * DH + quad * 8;
        qf[g][0] = *(const bf16x8*)qb;
        qf[g][1] = *(const bf16x8*)(qb + 32);
    }

    f32x4 O[2][4];
#pragma unroll
    for (int g = 0; g < 2; ++g)
#pragma unroll
        for (int dt = 0; dt < 4; ++dt) O[g][dt] = f32x4{0, 0, 0, 0};
    float lsum[2] = {0.f, 0.f};

    const unsigned short* kbase = kh + (size_t)bh * SEQ * DH + (size_t)half * 1024 * DH;
    const unsigned short* vbase = vt + (size_t)bh * DH * SEQ + half * 1024;
    const u64* mrow0 = mbits + ((size_t)b * SEQ + q0 + w * 32 + l15) * (SEQ / 64) + half * 16;
    const u64* mrow1 = mrow0 + 16 * (SEQ / 64);

    // prefetch tile 0 (K, V, mask) into registers
    uint4 pk0, pk1, pv0, pv1;
    u64 pm0, pm1;
    {
        const unsigned short* ks = kbase + (size_t)sr * DH + sp * 16;
        pk0 = *(const uint4*)ks; pk1 = *(const uint4*)(ks + 8);
        const unsigned short* vs = vbase + (size_t)sr * SEQ + sp * 16;
        pv0 = *(const uint4*)vs; pv1 = *(const uint4*)(vs + 8);
        pm0 = mrow0[0]; pm1 = mrow1[0];
    }

    for (int kt = 0; kt < 16; ++kt) {
        __syncthreads();                  // previous tile's readers done
        *(uint4*)&KtH[sr * 72 + sp * 16]     = pk0;
        *(uint4*)&KtH[sr * 72 + sp * 16 + 8] = pk1;
        *(uint4*)&VtH[sr * 72 + sp * 16]     = pv0;
        *(uint4*)&VtH[sr * 72 + sp * 16 + 8] = pv1;
        const u64 mb0 = pm0, mb1 = pm1;
        if (kt < 15) {                    // prefetch next tile during compute
            const unsigned short* ks = kbase + (size_t)((kt + 1) * 64 + sr) * DH + sp * 16;
            pk0 = *(const uint4*)ks; pk1 = *(const uint4*)(ks + 8);
            const unsigned short* vs = vbase + (size_t)sr * SEQ + (kt + 1) * 64 + sp * 16;
            pv0 = *(const uint4*)vs; pv1 = *(const uint4*)(vs + 8);
            pm0 = mrow0[kt + 1]; pm1 = mrow1[kt + 1];
        }
        __syncthreads();                  // tile staged

        // ---- S^T tiles + masked exp; P stays in registers ----
        bf16x4 p[2][4];
#pragma unroll
        for (int st = 0; st < 4; ++st) {
            bf16x8 kf0 = *(const bf16x8*)&KtH[(st * 16 + l15) * 72 + quad * 8];
            bf16x8 kf1 = *(const bf16x8*)&KtH[(st * 16 + l15) * 72 + 32 + quad * 8];
#pragma unroll
            for (int g = 0; g < 2; ++g) {
                f32x4 sa = {0, 0, 0, 0};
                sa = __builtin_amdgcn_mfma_f32_16x16x32_bf16(kf0, qf[g][0], sa, 0, 0, 0);
                sa = __builtin_amdgcn_mfma_f32_16x16x32_bf16(kf1, qf[g][1], sa, 0, 0, 0);
                const unsigned nib = (unsigned)((g ? mb1 : mb0) >> (st * 16 + quad * 4)) & 0xFu;
                float p0 = (nib & 1u) ? __expf(sa[0] * 0.125f) : 0.f;
                float p1 = (nib & 2u) ? __expf(sa[1] * 0.125f) : 0.f;
                float p2 = (nib & 4u) ? __expf(sa[2] * 0.125f) : 0.f;
                float p3 = (nib & 8u) ? __expf(sa[3] * 0.125f) : 0.f;
                lsum[g] += (p0 + p1) + (p2 + p3);
                union { __hip_bfloat162 h2[2]; bf16x4 v; } pu;
                pu.h2[0] = __float22bfloat162_rn(make_float2(p0, p1));
                pu.h2[1] = __float22bfloat162_rn(make_float2(p2, p3));
                p[g][st] = pu.v;
            }
        }

        // ---- PV: O[g][dt] += P * V ----
#pragma unroll
        for (int dt = 0; dt < 4; ++dt) {
#pragma unroll
            for (int st = 0; st < 4; ++st) {
                bf16x4 vb = *(const bf16x4*)&VtH[(dt * 16 + l15) * 72 + st * 16 + quad * 4];
                O[0][dt] = __builtin_amdgcn_mfma_f32_16x16x16bf16_1k(p[0][st], vb, O[0][dt], 0, 0, 0);
                O[1][dt] = __builtin_amdgcn_mfma_f32_16x16x16bf16_1k(p[1][st], vb, O[1][dt], 0, 0, 0);
            }
        }
    }

    // ---- merge halves through LDS, normalize, store ----
    float lr[2];
#pragma unroll
    for (int g = 0; g < 2; ++g) {
        lr[g] = lsum[g];
        lr[g] += __shfl_xor(lr[g], 16);
        lr[g] += __shfl_xor(lr[g], 32);   // per-row half-sum in every lane (row l15 of group g)
    }

    float* Obuf = (float*)smem4;          // [128][66] f32
    float* Ls   = ((float*)smem4) + 128 * 66;  // [128]

    __syncthreads();                      // all K/V reads complete
    if (half == 0) {
#pragma unroll
        for (int g = 0; g < 2; ++g)
#pragma unroll
            for (int dt = 0; dt < 4; ++dt)
#pragma unroll
                for (int r = 0; r < 4; ++r)
                    Obuf[(w * 32 + g * 16 + quad * 4 + r) * 66 + dt * 16 + l15] = O[g][dt][r];
        if (quad == 0) {
            Ls[w * 32 + l15]      = lr[0];
            Ls[w * 32 + 16 + l15] = lr[1];
        }
    }
    __syncthreads();
    if (half == 1) {
#pragma unroll
        for (int g = 0; g < 2; ++g) {
            const float ltot = lr[g] + Ls[w * 32 + g * 16 + l15];
            const float invl = 1.0f / ltot;
            float invr[4];
#pragma unroll
            for (int r = 0; r < 4; ++r) invr[r] = __shfl(invl, quad * 4 + r);
#pragma unroll
            for (int r = 0; r < 4; ++r) {
                const int row = w * 32 + g * 16 + quad * 4 + r;
                unsigned short* dst = ctx + ((size_t)bh * SEQ + q0 + row) * DH + l15;
#pragma unroll
                for (int dt = 0; dt < 4; ++dt) {
                    const float val = O[g][dt][r] + Obuf[row * 66 + dt * 16 + l15];
                    dst[dt * 16] = f2bf(val * invr[r]);
                }
            }
        }
    }
}

// ---------------------------------------------------------------------------
// Kernel 6: output projection via MFMA (verified R3/R5).
// ---------------------------------------------------------------------------
__global__ __launch_bounds__(256) void outproj_mfma(
    const unsigned short* __restrict__ ctx, const unsigned short* __restrict__ Wob,
    const float* __restrict__ bo, float* __restrict__ out)
{
    const int n0 = blockIdx.x * 64;
    const int m0 = blockIdx.y * 64;
    const int b  = m0 / SEQ;
    const int s0 = m0 % SEQ;

    __shared__ unsigned short At[64 * 72];
    __shared__ unsigned short Wt[64 * 72];

    const int t    = threadIdx.x;
    const int w    = t >> 6;
    const int lane = t & 63;
    const int l15  = lane & 15;
    const int quad = lane >> 4;
    const int sr = t >> 2, sp = t & 3;

    f32x4 acc[4] = {f32x4{0,0,0,0}, f32x4{0,0,0,0}, f32x4{0,0,0,0}, f32x4{0,0,0,0}};

    for (int kt = 0; kt < HEADS; ++kt) {
        __syncthreads();
        {
            const unsigned short* as =
                ctx + (((size_t)b * HEADS + kt) * SEQ + s0 + sr) * DH + sp * 16;
            *(uint4*)&At[sr * 72 + sp * 16]     = *(const uint4*)as;
            *(uint4*)&At[sr * 72 + sp * 16 + 8] = *(const uint4*)(as + 8);
            const unsigned short* wsrc =
                Wob + (size_t)(n0 + sr) * EMBED + kt * 64 + sp * 16;
            *(uint4*)&Wt[sr * 72 + sp * 16]     = *(const uint4*)wsrc;
            *(uint4*)&Wt[sr * 72 + sp * 16 + 8] = *(const uint4*)(wsrc + 8);
        }
        __syncthreads();

        bf16x8 bf0 = *(const bf16x8*)&Wt[(w * 16 + l15) * 72 + quad * 8];
        bf16x8 bf1 = *(const bf16x8*)&Wt[(w * 16 + l15) * 72 + 32 + quad * 8];
#pragma unroll
        for (int mt = 0; mt < 4; ++mt) {
            bf16x8 af0 = *(const bf16x8*)&At[(mt * 16 + l15) * 72 + quad * 8];
            bf16x8 af1 = *(const bf16x8*)&At[(mt * 16 + l15) * 72 + 32 + quad * 8];
            acc[mt] = __builtin_amdgcn_mfma_f32_16x16x32_bf16(af0, bf0, acc[mt], 0, 0, 0);
            acc[mt] = __builtin_amdgcn_mfma_f32_16x16x32_bf16(af1, bf1, acc[mt], 0, 0, 0);
        }
    }

    const float bv = bo[n0 + w * 16 + l15];
#pragma unroll
    for (int mt = 0; mt < 4; ++mt) {
#pragma unroll
        for (int r = 0; r < 4; ++r) {
            out[(size_t)(m0 + mt * 16 + quad * 4 + r) * EMBED + n0 + w * 16 + l15] =
                acc[mt][r] + bv;
        }
    }
}

// ---------------------------------------------------------------------------
extern "C" void kernel_launch(void* const* d_in, const int* in_sizes, int n_in,
                              void* d_out, int out_size, void* d_ws, size_t ws_size,
                              hipStream_t stream) {
    const float* k    = (const float*)d_in[0];
    const float* q    = (const float*)d_in[1];
    const float* v    = (const float*)d_in[2];
    const int*   mask = (const int*)  d_in[3];
    const float* Wk   = (const float*)d_in[4];
    const float* bk   = (const float*)d_in[5];
    const float* Wq   = (const float*)d_in[6];
    const float* bq   = (const float*)d_in[7];
    const float* Wv   = (const float*)d_in[8];
    const float* bv   = (const float*)d_in[9];
    const float* Wo   = (const float*)d_in[10];
    const float* bo   = (const float*)d_in[11];
    float* out = (float*)d_out;

    const size_t TEN = (size_t)BATCH * HEADS * SEQ * DH;   // 4,194,304 elems
    unsigned short* qh_bf = (unsigned short*)d_ws;         // 8 MB
    unsigned short* kh_bf = qh_bf + TEN;                   // 8 MB
    unsigned short* vh_bf = kh_bf + TEN;                   // 8 MB
    unsigned short* vt_bf = vh_bf + TEN;                   // 8 MB
    unsigned short* ctxb  = vt_bf + TEN;                   // 8 MB
    unsigned short* Wob   = ctxb + TEN;                    // 2 MB
    u64*            mbits = (u64*)(Wob + EMBED * EMBED);   // 1 MB  (43 MB total)

    proj_mfma<<<dim3(BATCH * SEQ * HEADS / 64, 3), 256, 0, stream>>>(
        q, k, v, Wq, bq, Wk, bk, Wv, bv, qh_bf, kh_bf, vh_bf);
    vtrans_kernel<<<dim3(SEQ / 64, BATCH * HEADS), 256, 0, stream>>>(vh_bf, vt_bf);
    maskpack_kernel<<<dim3((BATCH * SEQ * (SEQ / 64)) / 256), 256, 0, stream>>>(mask, mbits);
    wcvt_kernel<<<dim3(EMBED * EMBED / (256 * 8)), 256, 0, stream>>>(Wo, Wob);
    attn_kernel<<<dim3((SEQ / 128) * BATCH * HEADS), 512, 0, stream>>>(
        qh_bf, kh_bf, vt_bf, mbits, ctxb);
    outproj_mfma<<<dim3(EMBED / 64, BATCH * SEQ / 64), 256, 0, stream>>>(
        ctxb, Wob, bo, out);
}